// Round 1
// baseline (63.635 us; speedup 1.0000x reference)
//
#include <hip/hip_runtime.h>
#include <math.h>

#define NPTS 262144
#define K 32
#define D 16
#define NU 136        // packed upper-triangle count of 16x16 symmetric
#define PSTRIDE 160   // per-k param stride (floats): G[16], U[136], lc, pad
#define LC_OFF (D + NU)   // 152

// ---------------- prep kernel: one block per component k ----------------
// Computes, all in double, then stores float (pre-scaled by log2(e)):
//   G[d]   = log2e * (L m)[d]
//   U[d<=f]= log2e * (d==f ? -0.5*L[d][d] : -L[d][f])
//   lc     = log2e * ( logsoftmax(p)[k] - 8*log(2pi) + log|det A| - 8*log(16)
//                      - 0.5 * m^T L m )
// so that density(x) = sum_k exp2( lc + G.x + x^T U x )
__global__ __launch_bounds__(256) void gm_prep_kernel(
    const float* __restrict__ m_w,      // K*D
    const float* __restrict__ l_fac,    // K*D*D
    const float* __restrict__ p_logits, // K
    float* __restrict__ params)         // K*PSTRIDE
{
  const int k = blockIdx.x;
  const int tid = threadIdx.x;
  const int r = tid >> 4, c = tid & 15;
  __shared__ double A[D][D];
  __shared__ double L[D][D];
  __shared__ double W[D][D];   // Cholesky workspace
  __shared__ double Gd[D];
  const double LOG2E = 1.4426950408889634074;

  A[r][c] = (double)l_fac[k * D * D + r * D + c];
  __syncthreads();

  // L = A A^T / D  (full symmetric, one entry per thread)
  {
    double s = 0.0;
    #pragma unroll
    for (int e = 0; e < D; ++e) s += A[r][e] * A[c][e];
    s /= (double)D;
    L[r][c] = s;
    W[r][c] = s;
  }
  __syncthreads();

  // G = L m (double kept in Gd for the m^T L m fold)
  if (tid < D) {
    double s = 0.0;
    #pragma unroll
    for (int f = 0; f < D; ++f) s += L[tid][f] * (double)m_w[k * D + f];
    Gd[tid] = s;
    params[k * PSTRIDE + tid] = (float)(LOG2E * s);
  }

  // packed upper-tri coefficients of -0.5 * x^T L x
  for (int idx = tid; idx < NU; idx += 256) {
    int d = 0, base = 0;
    while (base + (D - d) <= idx) { base += D - d; ++d; }
    int f = d + (idx - base);
    double u = (d == f) ? -0.5 * L[d][f] : -1.0 * L[d][f];
    params[k * PSTRIDE + D + idx] = (float)(LOG2E * u);
  }

  // Cholesky of W (PSD, no pivoting needed) for log sqrt(det L) = sum log C_jj
  for (int j = 0; j < D; ++j) {
    __syncthreads();
    if (tid == 0) W[j][j] = sqrt(W[j][j]);
    __syncthreads();
    if (tid > j && tid < D) W[tid][j] /= W[j][j];
    __syncthreads();
    if (r > j && c > j && c <= r) W[r][c] -= W[r][j] * W[c][j];
  }
  __syncthreads();

  if (tid == 0) {
    double logdet_sqrtL = 0.0;
    for (int j = 0; j < D; ++j) logdet_sqrtL += log(W[j][j]);
    // log-softmax over the K logits (redundant per block; trivial work)
    double mx = -1e300;
    for (int i = 0; i < K; ++i) mx = fmax(mx, (double)p_logits[i]);
    double z = 0.0;
    for (int i = 0; i < K; ++i) z += exp((double)p_logits[i] - mx);
    double logp = (double)p_logits[k] - mx - log(z);
    double cc = 0.0;                       // m^T L m
    for (int d2 = 0; d2 < D; ++d2) cc += (double)m_w[k * D + d2] * Gd[d2];
    double lc = logp - 8.0 * log(2.0 * M_PI) + logdet_sqrtL - 0.5 * cc;
    params[k * PSTRIDE + LC_OFF] = (float)(LOG2E * lc);
  }
}

// ---------------- main kernel: 2 points per thread ----------------
__global__ __launch_bounds__(256) void gm_density_kernel(
    const float* __restrict__ x,       // N*D
    const float* __restrict__ params,  // K*PSTRIDE
    float* __restrict__ out)           // N
{
  const int tid = threadIdx.x;
  const int n0 = blockIdx.x * 512 + tid;
  const int n1 = n0 + 256;

  float xa[D], xb[D];
  const float4* xpa = (const float4*)(x + (size_t)n0 * D);
  const float4* xpb = (const float4*)(x + (size_t)n1 * D);
  #pragma unroll
  for (int i = 0; i < 4; ++i) {
    float4 va = xpa[i];
    xa[4 * i + 0] = va.x; xa[4 * i + 1] = va.y;
    xa[4 * i + 2] = va.z; xa[4 * i + 3] = va.w;
    float4 vb = xpb[i];
    xb[4 * i + 0] = vb.x; xb[4 * i + 1] = vb.y;
    xb[4 * i + 2] = vb.z; xb[4 * i + 3] = vb.w;
  }

  float suma = 0.f, sumb = 0.f;
  for (int k = 0; k < K; ++k) {
    const float* __restrict__ pk = params + k * PSTRIDE;
    float ea = pk[LC_OFF];
    float eb = ea;
    const float* __restrict__ U = pk + D;
    int ui = 0;
    #pragma unroll
    for (int d = 0; d < D; ++d) {
      float ta = pk[d], tb = pk[d];
      #pragma unroll
      for (int f = d; f < D; ++f) {
        float u = U[ui++];
        ta = fmaf(u, xa[f], ta);
        tb = fmaf(u, xb[f], tb);
      }
      ea = fmaf(xa[d], ta, ea);
      eb = fmaf(xb[d], tb, eb);
    }
    suma += exp2f(ea);
    sumb += exp2f(eb);
  }
  out[n0] = suma;
  out[n1] = sumb;
}

extern "C" void kernel_launch(void* const* d_in, const int* in_sizes, int n_in,
                              void* d_out, int out_size, void* d_ws, size_t ws_size,
                              hipStream_t stream) {
  const float* x        = (const float*)d_in[0];
  const float* m_w      = (const float*)d_in[1];
  const float* l_fac    = (const float*)d_in[2];
  const float* p_logits = (const float*)d_in[3];
  float* out = (float*)d_out;
  float* params = (float*)d_ws;   // K*PSTRIDE floats = 20 KiB

  gm_prep_kernel<<<K, 256, 0, stream>>>(m_w, l_fac, p_logits, params);
  gm_density_kernel<<<NPTS / 512, 256, 0, stream>>>(x, params, out);
}

// Round 2
// 60.479 us; speedup vs baseline: 1.0522x; 1.0522x over previous
//
#include <hip/hip_runtime.h>
#include <math.h>

#define NPTS 262144
#define K 32
#define D 16
#define NU 136        // packed upper-triangle count of 16x16 symmetric
#define PSTRIDE 160   // per-k param stride (floats): G[16], U[136], lc, pad
#define LC_OFF (D + NU)   // 152

// ---------------- prep kernel: one block per component k ----------------
// Computes, all in double, then stores float (pre-scaled by log2(e)):
//   G[d]   = log2e * (L m)[d]
//   U[d<=f]= log2e * (d==f ? -0.5*L[d][d] : -L[d][f])
//   lc     = log2e * ( logsoftmax(p)[k] - 8*log(2pi) + log sqrt(det L)
//                      - 0.5 * m^T L m )
// so that density(x) = sum_k exp2( lc + G.x + x^T U x )
__global__ __launch_bounds__(256) void gm_prep_kernel(
    const float* __restrict__ m_w,      // K*D
    const float* __restrict__ l_fac,    // K*D*D
    const float* __restrict__ p_logits, // K
    float* __restrict__ params)         // K*PSTRIDE
{
  const int k = blockIdx.x;
  const int tid = threadIdx.x;
  const int r = tid >> 4, c = tid & 15;
  __shared__ double A[D][D];
  __shared__ double L[D][D];
  __shared__ double W[D][D];   // Cholesky workspace
  __shared__ double Gd[D];
  const double LOG2E = 1.4426950408889634074;

  A[r][c] = (double)l_fac[k * D * D + r * D + c];
  __syncthreads();

  // L = A A^T / D  (full symmetric, one entry per thread)
  {
    double s = 0.0;
    #pragma unroll
    for (int e = 0; e < D; ++e) s += A[r][e] * A[c][e];
    s /= (double)D;
    L[r][c] = s;
    W[r][c] = s;
  }
  __syncthreads();

  // G = L m (double kept in Gd for the m^T L m fold)
  if (tid < D) {
    double s = 0.0;
    #pragma unroll
    for (int f = 0; f < D; ++f) s += L[tid][f] * (double)m_w[k * D + f];
    Gd[tid] = s;
    params[k * PSTRIDE + tid] = (float)(LOG2E * s);
  }

  // packed upper-tri coefficients of -0.5 * x^T L x
  for (int idx = tid; idx < NU; idx += 256) {
    int d = 0, base = 0;
    while (base + (D - d) <= idx) { base += D - d; ++d; }
    int f = d + (idx - base);
    double u = (d == f) ? -0.5 * L[d][f] : -1.0 * L[d][f];
    params[k * PSTRIDE + D + idx] = (float)(LOG2E * u);
  }

  // Cholesky of W (PSD, no pivoting needed) for log sqrt(det L) = sum log C_jj
  for (int j = 0; j < D; ++j) {
    __syncthreads();
    if (tid == 0) W[j][j] = sqrt(W[j][j]);
    __syncthreads();
    if (tid > j && tid < D) W[tid][j] /= W[j][j];
    __syncthreads();
    if (r > j && c > j && c <= r) W[r][c] -= W[r][j] * W[c][j];
  }
  __syncthreads();

  if (tid == 0) {
    double logdet_sqrtL = 0.0;
    for (int j = 0; j < D; ++j) logdet_sqrtL += log(W[j][j]);
    // log-softmax over the K logits (redundant per block; trivial work)
    double mx = -1e300;
    for (int i = 0; i < K; ++i) mx = fmax(mx, (double)p_logits[i]);
    double z = 0.0;
    for (int i = 0; i < K; ++i) z += exp((double)p_logits[i] - mx);
    double logp = (double)p_logits[k] - mx - log(z);
    double cc = 0.0;                       // m^T L m
    for (int d2 = 0; d2 < D; ++d2) cc += (double)m_w[k * D + d2] * Gd[d2];
    double lc = logp - 8.0 * log(2.0 * M_PI) + logdet_sqrtL - 0.5 * cc;
    params[k * PSTRIDE + LC_OFF] = (float)(LOG2E * lc);
  }
}

// ---------------- main kernel: 1 point per thread, 1024 blocks ----------------
// 4096 waves over 1024 SIMDs = 4 waves/SIMD: TLP hides the dependent-FMA
// chain latency and the per-k s_load waits.
__global__ __launch_bounds__(256) void gm_density_kernel(
    const float* __restrict__ x,       // N*D
    const float* __restrict__ params,  // K*PSTRIDE
    float* __restrict__ out)           // N
{
  const int n = blockIdx.x * 256 + threadIdx.x;

  float xa[D];
  const float4* xp = (const float4*)(x + (size_t)n * D);
  #pragma unroll
  for (int i = 0; i < 4; ++i) {
    float4 v = xp[i];
    xa[4 * i + 0] = v.x; xa[4 * i + 1] = v.y;
    xa[4 * i + 2] = v.z; xa[4 * i + 3] = v.w;
  }

  float suma = 0.f;
  for (int k = 0; k < K; ++k) {
    const float* __restrict__ pk = params + k * PSTRIDE;
    float ea = pk[LC_OFF];
    const float* __restrict__ U = pk + D;
    int ui = 0;
    #pragma unroll
    for (int d = 0; d < D; ++d) {
      float ta = pk[d];
      #pragma unroll
      for (int f = d; f < D; ++f) {
        float u = U[ui++];
        ta = fmaf(u, xa[f], ta);
      }
      ea = fmaf(xa[d], ta, ea);
    }
    suma += exp2f(ea);
  }
  out[n] = suma;
}

extern "C" void kernel_launch(void* const* d_in, const int* in_sizes, int n_in,
                              void* d_out, int out_size, void* d_ws, size_t ws_size,
                              hipStream_t stream) {
  const float* x        = (const float*)d_in[0];
  const float* m_w      = (const float*)d_in[1];
  const float* l_fac    = (const float*)d_in[2];
  const float* p_logits = (const float*)d_in[3];
  float* out = (float*)d_out;
  float* params = (float*)d_ws;   // K*PSTRIDE floats = 20 KiB

  gm_prep_kernel<<<K, 256, 0, stream>>>(m_w, l_fac, p_logits, params);
  gm_density_kernel<<<NPTS / 256, 256, 0, stream>>>(x, params, out);
}